// Round 11
// baseline (121.556 us; speedup 1.0000x reference)
//
#include <hip/hip_runtime.h>

typedef _Float16 f16x8 __attribute__((ext_vector_type(8)));
typedef float f32x4 __attribute__((ext_vector_type(4)));

#define B_  8
#define LQ  2048
#define LC  4096
#define DD  256

// async global->LDS, 16B per lane. LDS dest is wave-uniform base + lane*16.
__device__ __forceinline__ void gload_lds16(const void* g, void* l) {
    __builtin_amdgcn_global_load_lds(
        (const __attribute__((address_space(1))) unsigned int*)g,
        (__attribute__((address_space(3))) unsigned int*)l,
        16, 0, 0);
}

// Convert query only (context is consumed as f32 directly by gemm + out).
// Also zeroes `out` (out_kernel's atomicAdds run two kernels later).
__global__ __launch_bounds__(256)
void convert_q(const float* __restrict__ q, _Float16* __restrict__ qf,
               float* __restrict__ out) {
    if (blockIdx.x < 8) out[blockIdx.x * 256 + threadIdx.x] = 0.f;
    const int i = (blockIdx.x * 256 + threadIdx.x) * 8;   // 2048 blocks cover 8*2048*256
    const float4 a = *(const float4*)(q + i);
    const float4 c = *(const float4*)(q + i + 4);
    f16x8 o;
    o[0] = (_Float16)a.x; o[1] = (_Float16)a.y; o[2] = (_Float16)a.z; o[3] = (_Float16)a.w;
    o[4] = (_Float16)c.x; o[5] = (_Float16)c.y; o[6] = (_Float16)c.z; o[7] = (_Float16)c.w;
    *(f16x8*)(qf + i) = o;
}

// R11 = R10 resubmit (R10 bench was an infra failure) + one correctness fix:
// a TRAILING barrier after each chunk's phase-B MFMA cluster, completing the
// m201 two-barrier phase shape {reads; stage; barrier; lgkm0; MFMA; barrier}.
// Without it, phase A(c)'s STAGE into buf (c-1)&3 races other threads'
// still-pending phase-B(c-1) ds_reads of that buffer (reads are issued
// pre-barrier, waited post-barrier).
//
// Structure (T3+T4, m196/m218): per chunk c (buf c&3, 4 bufs):
//  phase A: {4 ds_read ksl0; STAGE(c+3); s_barrier; lgkm0; prio; 16 MFMA; prio}
//  phase B: {4 ds_read ksl1; vmcnt(4)+s_barrier (retires c+1); lgkm0; prio;
//            16 MFMA; prio; s_barrier}
// Ledger: at phase-B vmcnt, outstanding = chunks c+1..c+3 = 6 insts ->
// vmcnt(4) retires exactly c+1 (read next chunk). Tail c=29/30+: 2/0.
// Everything else is R9-verified: A-prologue ledger, R2 XOR tile layout,
// depth-3 staging, BM=256/BN=1024, epilogue, per-qh scores.
__global__ __launch_bounds__(512, 2)
void gemm_max_kernel(const _Float16* __restrict__ qf,
                     const float* __restrict__ ctx,
                     float* __restrict__ scores) {
    __shared__ __align__(16) _Float16 Buf[4][8192];   // 4 x 16 KB
    __shared__ float red[2][256];

    const int bid = blockIdx.x;
    const int b   = bid & 7;          // XCD affinity: batch b -> XCD b
    const int mt  = (bid >> 3) & 15;  // ctx tile 0..15 (256 rows)
    const int qh  = bid >> 7;         // query half 0..1 (1024 q each)

    const int tid  = threadIdx.x;
    const int lane = tid & 63;
    const int wave = tid >> 6;   // 0..7
    const int wm   = wave >> 1;  // ctx slot (0..3) -> 64 rows each
    const int wn   = wave & 1;   // q slot   (0..1) -> 64 cols each
    const int quad = lane >> 4;
    const int l15  = lane & 15;

    const float*    Ag = ctx + ((size_t)b * LC + (size_t)mt * 256) * DD;
    const _Float16* Bg = qf  + ((size_t)b * LQ + (size_t)qh * 1024) * DD;

    // staging map (R2-verified): 512 threads x 16B x 2 passes = 16KB chunk.
    const int srow    = tid >> 3;    // 0..63
    const int g_store = tid & 7;
    const int g_glob  = g_store ^ (srow & 7);

    // A chunk ac = h*8 + j: ctx rows [h*128, +128), k [j*32, +32) f32
#define STAGE_A(ac, bufi)                                                       \
    {                                                                           \
        const float* _a = Ag + (size_t)((ac) >> 3) * 128 * DD + ((ac) & 7) * 32; \
        _Pragma("unroll")                                                       \
        for (int p = 0; p < 2; ++p)                                             \
            gload_lds16(_a + (size_t)(p * 64 + srow) * DD + g_glob * 4,         \
                        (char*)Buf[bufi] + p * 8192 + tid * 16);                \
    }

    // B chunk c (c = nt*4 + kc): q rows [nt*128, +128) of this half, k [kc*64, +64)
#define STAGE_B(c, bufi)                                                        \
    {                                                                           \
        const _Float16* _s = Bg + (size_t)((c) >> 2) * 128 * DD + ((c) & 3) * 64; \
        _Pragma("unroll")                                                       \
        for (int p = 0; p < 2; ++p)                                             \
            gload_lds16(_s + (size_t)(p * 64 + srow) * DD + g_glob * 8,         \
                        (char*)Buf[bufi] + p * 8192 + tid * 16);                \
    }

    // counted-vmcnt barrier (rule 18: sched_barrier fences on both sides)
#define SYNCV(N)                                                                \
    {                                                                           \
        __builtin_amdgcn_sched_barrier(0);                                      \
        asm volatile("s_waitcnt vmcnt(" #N ")" ::: "memory");                   \
        __builtin_amdgcn_s_barrier();                                           \
        __builtin_amdgcn_sched_barrier(0);                                      \
    }

    // bare barrier (no waitcnt -- loads stay in flight across it)
#define BARR                                                                    \
    {                                                                           \
        __builtin_amdgcn_sched_barrier(0);                                      \
        __builtin_amdgcn_s_barrier();                                           \
        __builtin_amdgcn_sched_barrier(0);                                      \
    }

#define LGKM0                                                                   \
    {                                                                           \
        asm volatile("s_waitcnt lgkmcnt(0)" ::: "memory");                      \
        __builtin_amdgcn_sched_barrier(0);                                      \
    }

    f16x8 af[4][8];   // A fragments: rows wm*64+mi*16+l15, k = j*32+quad*8+e
    f32x4 acc[4][4];
    float rm[4][4];

    // fill af[*][j] from f32 A chunk (in Buf[bufi], rows are chunk-local).
#define FILL_A(j, bufi)                                                         \
    {                                                                           \
        _Pragma("unroll")                                                       \
        for (int mi = 0; mi < 4; ++mi) {                                        \
            const int row = (wm & 1) * 64 + mi * 16 + l15;                      \
            const int p0  = (2 * quad) ^ (row & 7);                             \
            const int p1  = (2 * quad + 1) ^ (row & 7);                         \
            const f32x4 v0 = *(const f32x4*)((const char*)Buf[bufi] + row * 128 + p0 * 16); \
            const f32x4 v1 = *(const f32x4*)((const char*)Buf[bufi] + row * 128 + p1 * 16); \
            f16x8 o;                                                            \
            o[0] = (_Float16)v0[0]; o[1] = (_Float16)v0[1];                     \
            o[2] = (_Float16)v0[2]; o[3] = (_Float16)v0[3];                     \
            o[4] = (_Float16)v1[0]; o[5] = (_Float16)v1[1];                     \
            o[6] = (_Float16)v1[2]; o[7] = (_Float16)v1[3];                     \
            af[mi][j] = o;                                                      \
        }                                                                       \
    }

    // 4 ds_read_b128 of one ksl's B fragments from Buf[bufi]
#define READ_B(dst, ksl, bufi)                                                  \
    {                                                                           \
        _Pragma("unroll")                                                       \
        for (int ni = 0; ni < 4; ++ni) {                                        \
            const int row = wn * 64 + ni * 16 + l15;                            \
            const int pos = ((ksl) * 4 + quad) ^ (row & 7);                     \
            dst[ni] = *(const f16x8*)((const char*)Buf[bufi] + row * 128 + pos * 16); \
        }                                                                       \
    }

    // 16-MFMA cluster
#define MFMA16(src, kf)                                                         \
    {                                                                           \
        __builtin_amdgcn_s_setprio(1);                                          \
        _Pragma("unroll")                                                       \
        for (int mi = 0; mi < 4; ++mi)                                          \
            _Pragma("unroll")                                                   \
            for (int ni = 0; ni < 4; ++ni)                                      \
                acc[mi][ni] = __builtin_amdgcn_mfma_f32_16x16x32_f16(           \
                    af[mi][kf], src[ni], acc[mi][ni], 0, 0, 0);                 \
        __builtin_amdgcn_s_setprio(0);                                          \
    }

#pragma unroll
    for (int mi = 0; mi < 4; ++mi) {
#pragma unroll
        for (int r = 0; r < 4; ++r) rm[mi][r] = -3.4e38f;
#pragma unroll
        for (int ni = 0; ni < 4; ++ni) acc[mi][ni] = (f32x4)0.0f;
    }

    // ---- A prologue (R9-verified): 16 chunks through 4 buffers, SYNCV(4).
    // Slots 13..15 stage B0..B2 -> bufs 0..2. After loop: outstanding = 6.
    STAGE_A(0, 0); STAGE_A(1, 1); STAGE_A(2, 2);
#pragma unroll
    for (int ac = 0; ac < 16; ++ac) {
        SYNCV(4);
        if (ac < 13) { STAGE_A(ac + 3, (ac + 3) & 3); }
        else         { STAGE_B(ac - 13, (ac - 13) & 3); }
        if ((wave >> 2) == (ac >> 3)) FILL_A(ac & 7, ac & 3);
    }
    SYNCV(4);   // retire chunk B0 (outstanding -> B1,B2) before its reads

    // ---- main: 8 q-tiles x 4 K-chunks x 2 phases (m201 two-barrier shape)
#pragma unroll 1
    for (int nt = 0; nt < 8; ++nt) {
#pragma unroll
        for (int kc = 0; kc < 4; ++kc) {
            const int c = nt * 4 + kc;
            // phase A: reads ksl0 + stage + bare barrier + MFMA
            f16x8 bfv0[4];
            READ_B(bfv0, 0, kc);
            if (c + 3 < 32) STAGE_B(c + 3, (c + 3) & 3);
            BARR;
            LGKM0;
            MFMA16(bfv0, kc * 2);
            // phase B: reads ksl1 + counted vmcnt barrier + MFMA + trailing
            // barrier (all reads of buf kc complete before its re-stage)
            f16x8 bfv1[4];
            READ_B(bfv1, 1, kc);
            if (c < 29)      { SYNCV(4); }   // retire c+1
            else if (c == 29){ SYNCV(2); }   // retire 30
            else             { SYNCV(0); }   // retire 31 / drain
            LGKM0;
            MFMA16(bfv1, kc * 2 + 1);
            BARR;                            // WAR fence for buf kc re-stage
        }
        // fold q-tile into running row max; reset acc
#pragma unroll
        for (int mi = 0; mi < 4; ++mi)
#pragma unroll
            for (int r = 0; r < 4; ++r) {
                rm[mi][r] = fmaxf(rm[mi][r],
                                  fmaxf(fmaxf(acc[mi][0][r], acc[mi][1][r]),
                                        fmaxf(acc[mi][2][r], acc[mi][3][r])));
                acc[mi][0][r] = 0.f; acc[mi][1][r] = 0.f;
                acc[mi][2][r] = 0.f; acc[mi][3][r] = 0.f;
            }
    }

    // ---- epilogue: reduce over the 16 q-col lanes, then the two wn slots
#pragma unroll
    for (int sh = 1; sh <= 8; sh <<= 1)
#pragma unroll
        for (int mi = 0; mi < 4; ++mi)
#pragma unroll
            for (int r = 0; r < 4; ++r)
                rm[mi][r] = fmaxf(rm[mi][r], __shfl_xor(rm[mi][r], sh, 64));

    if (l15 == 0) {
#pragma unroll
        for (int mi = 0; mi < 4; ++mi)
#pragma unroll
            for (int r = 0; r < 4; ++r)
                red[wn][wm * 64 + mi * 16 + quad * 4 + r] = rm[mi][r];
    }
    __syncthreads();
    if (tid < 256)
        scores[(size_t)qh * (B_ * LC) + (size_t)b * LC + mt * 256 + tid] =
            fmaxf(red[0][tid], red[1][tid]);

#undef STAGE_A
#undef STAGE_B
#undef SYNCV
#undef BARR
#undef LGKM0
#undef FILL_A
#undef READ_B
#undef MFMA16
}

// Fused softmax-stats + weighted context sum. scores come in two q-half
// buffers; final score = fmax of the two. Each block recomputes M and the
// softmax denominator (16 KB, L2-hit, deterministic -> identical across
// blocks), then accumulates its 64-row chunk of
// out[b][d] = sum_c softmax(scores)[c] * ctx[b][c][d]   (ctx read as f32).
__global__ __launch_bounds__(256)
void out_kernel(const float* __restrict__ scores, const float* __restrict__ ctx,
                float* __restrict__ out) {
    const int ch   = blockIdx.x;   // 0..63
    const int b    = blockIdx.y;   // 0..7
    const int tid  = threadIdx.x;
    const int lane = tid & 63;
    const int wave = tid >> 6;
    __shared__ float smax[4];
    __shared__ float ssum[4];
    __shared__ float pl[64];

    const float* sb0 = scores + (size_t)b * LC;
    const float* sb1 = sb0 + (size_t)B_ * LC;

    float sv[16];
    float lmax = -3.4e38f;
#pragma unroll
    for (int j = 0; j < 16; ++j) {
        const int c = tid + j * 256;
        sv[j] = fmaxf(sb0[c], sb1[c]);
        lmax  = fmaxf(lmax, sv[j]);
    }
    for (int sh = 1; sh < 64; sh <<= 1)
        lmax = fmaxf(lmax, __shfl_xor(lmax, sh, 64));
    if (lane == 0) smax[wave] = lmax;
    __syncthreads();
    const float M = fmaxf(fmaxf(smax[0], smax[1]), fmaxf(smax[2], smax[3]));

    float lsum = 0.f;
#pragma unroll
    for (int j = 0; j < 16; ++j)
        lsum += expf(sv[j] - M);
    for (int sh = 1; sh < 64; sh <<= 1)
        lsum += __shfl_xor(lsum, sh, 64);
    if (lane == 0) ssum[wave] = lsum;
    __syncthreads();
    const float inv = 1.f / (ssum[0] + ssum[1] + ssum[2] + ssum[3]);

    if (tid < 64) {
        const int c = ch * 64 + tid;
        pl[tid] = expf(fmaxf(sb0[c], sb1[c]) - M) * inv;
    }
    __syncthreads();

    const float* cb = ctx + ((size_t)b * LC + (size_t)ch * 64) * DD;
    float acc = 0.f;
#pragma unroll 8
    for (int i = 0; i < 64; ++i)
        acc += pl[i] * cb[(size_t)i * DD + tid];   // coalesced f32
    atomicAdd(&out[b * DD + tid], acc);
}

extern "C" void kernel_launch(void* const* d_in, const int* in_sizes, int n_in,
                              void* d_out, int out_size, void* d_ws, size_t ws_size,
                              hipStream_t stream) {
    const float* q   = (const float*)d_in[0];   // [8, 2048, 256] f32
    const float* ctx = (const float*)d_in[1];   // [8, 4096, 256] f32
    float* out = (float*)d_out;                 // [8, 1, 256] f32

    // ws layout (bytes):
    //   qf     @ 0        : 8*2048*256*2 = 8,388,608
    //   scores @ 8388608  : 2*8*4096*4   =   262,144   (two q-half buffers)
    char* ws = (char*)d_ws;
    _Float16* qf  = (_Float16*)(ws);
    float* scores = (float*)(ws + 8388608);

    convert_q<<<2048, 256, 0, stream>>>(q, qf, out);
    gemm_max_kernel<<<256, 512, 0, stream>>>(qf, ctx, scores);
    out_kernel<<<dim3(64, 8), 256, 0, stream>>>(scores, ctx, out);
}